// Round 1
// baseline (273.475 us; speedup 1.0000x reference)
//
#include <hip/hip_runtime.h>

#define BATCH 4
#define CCH 128
#define NSP 4096
#define NGRP 8
#define GROUP_ELEMS 65536   // 16 ch * 4096
// ATT_SCALE * log2(e): folded into q at qkv_gemm so softmax is exp2(s)
#define QSCALE 0.12751744f
#define EPS_GN 1e-5f
#define KHN 8               // key-split count (8 partials)
#define OPSTRIDE 2097152    // 4*4096*128 shorts per kh partial
#define LPSTRIDE 16384      // 4*4096 floats per kh partial

typedef short s8b __attribute__((ext_vector_type(8)));
typedef float f32x4 __attribute__((ext_vector_type(4)));
typedef float f32x16 __attribute__((ext_vector_type(16)));

static __device__ __forceinline__ short f2bf(float f) {
  union { float f; unsigned u; } v; v.f = f;
  unsigned r = (v.u + 0x7FFFu + ((v.u >> 16) & 1u)) >> 16;
  return (short)r;
}

static __device__ __forceinline__ float bf2f(short s) {
  unsigned u = ((unsigned)(unsigned short)s) << 16;
  float f; __builtin_memcpy(&f, &u, 4); return f;
}

static __device__ __forceinline__ float fexp2(float x) {
#if __has_builtin(__builtin_amdgcn_exp2f)
  return __builtin_amdgcn_exp2f(x);
#else
  return exp2f(x);
#endif
}

// single-instruction pack of two f32 -> adjacent bf16 (RNE): lo=a, hi=b
static __device__ __forceinline__ unsigned cvtpk(float a, float b) {
  unsigned r;
  asm("v_cvt_pk_bf16_f32 %0, %1, %2" : "=v"(r) : "v"(a), "v"(b));
  return r;
}

static __device__ __forceinline__ s8b pack8(float a0, float a1, float a2, float a3,
                                            float a4, float a5, float a6, float a7) {
  union { unsigned u[4]; s8b v; } x;
  x.u[0] = cvtpk(a0, a1); x.u[1] = cvtpk(a2, a3);
  x.u[2] = cvtpk(a4, a5); x.u[3] = cvtpk(a6, a7);
  return x.v;
}

static __device__ __forceinline__ f32x4 mfma16(s8b a, s8b b, f32x4 c) {
  return __builtin_amdgcn_mfma_f32_16x16x32_bf16(a, b, c, 0, 0, 0);
}
static __device__ __forceinline__ f32x16 mfma32(s8b a, s8b b, f32x16 c) {
  return __builtin_amdgcn_mfma_f32_32x32x16_bf16(a, b, c, 0, 0, 0);
}

// async 16B global->LDS DMA; dest = wave-uniform base + lane*16
static __device__ __forceinline__ void async16(const void* g, void* l) {
  __builtin_amdgcn_global_load_lds(
      (const __attribute__((address_space(1))) void*)g,
      (__attribute__((address_space(3))) void*)l, 16, 0, 0);
}

// ---------------- GroupNorm pass 1: per-(b,g,chunk) partial sum/sumsq ----------------
__global__ void gn_stats(const float* __restrict__ x, float* __restrict__ part) {
  int bx = blockIdx.x;            // 256 = bg(32) * chunk(8)
  int ch = bx & 7, bg = bx >> 3;
  const float* base = x + (size_t)bg * GROUP_ELEMS + (size_t)ch * 8192;
  int t = threadIdx.x;
  float s = 0.f, ss = 0.f;
  #pragma unroll
  for (int i = 0; i < 8; ++i) {
    float4 v = *(const float4*)(base + i * 1024 + t * 4);
    s  += v.x + v.y + v.z + v.w;
    ss += v.x * v.x + v.y * v.y + v.z * v.z + v.w * v.w;
  }
  #pragma unroll
  for (int off = 1; off < 64; off <<= 1) {
    s  += __shfl_xor(s, off);
    ss += __shfl_xor(ss, off);
  }
  __shared__ float red[8];
  int w = t >> 6;
  if ((t & 63) == 0) { red[w * 2] = s; red[w * 2 + 1] = ss; }
  __syncthreads();
  if (t == 0) {
    part[bx * 2]     = red[0] + red[2] + red[4] + red[6];
    part[bx * 2 + 1] = red[1] + red[3] + red[5] + red[7];
  }
}

// ---------------- GroupNorm pass 2: reduce partials, normalize, write xn (b,n,c) bf16 ----------------
__global__ void gn_apply(const float* __restrict__ x, const float* __restrict__ gw,
                         const float* __restrict__ gb, const float* __restrict__ part,
                         short* __restrict__ xn) {
  int bx = blockIdx.x;            // 256 = b(4) g(8) ns(8)
  int ns = bx & 7, g = (bx >> 3) & 7, b = bx >> 6;
  int bg = b * NGRP + g;
  float s = 0.f, ss = 0.f;
  #pragma unroll
  for (int j = 0; j < 8; ++j) {
    s  += part[(bg * 8 + j) * 2];
    ss += part[(bg * 8 + j) * 2 + 1];
  }
  float mean = s * (1.f / GROUP_ELEMS);
  float var  = ss * (1.f / GROUP_ELEMS) - mean * mean;
  float inv  = rsqrtf(var + EPS_GN);
  int t = threadIdx.x;
  int cl = t & 15, n4 = t >> 4;
  int c = g * 16 + cl;
  float ga = gw[c] * inv;
  float be = gb[c] - mean * ga;
  const float* xr = x + (size_t)(b * CCH + c) * NSP;
  short* xo = xn + (size_t)b * NSP * CCH + c;
  #pragma unroll
  for (int i = 0; i < 8; ++i) {
    int n = ns * 512 + i * 64 + n4 * 4;
    float4 v = *(const float4*)(xr + n);
    xo[(size_t)(n + 0) * CCH] = f2bf(v.x * ga + be);
    xo[(size_t)(n + 1) * CCH] = f2bf(v.y * ga + be);
    xo[(size_t)(n + 2) * CCH] = f2bf(v.z * ga + be);
    xo[(size_t)(n + 3) * CCH] = f2bf(v.w * ga + be);
  }
}

// ---------------- Fused QKV: bx<1024 -> q,k (D[n][o]); else -> v (D[o][n], permuted key order) ----------------
// v is written TRANSPOSED (b,c,n); within each 16-key chunk the key order is
// permuted so flash's PV can consume P DIRECTLY from the S^T MFMA C-registers:
// orig key kk (0..15) -> pos = 8*((kk>>2)&1) + (kk&3) + 4*(kk>>3)
__global__ void qkv_gemm(const short* __restrict__ xn, const float* __restrict__ Wqkv,
                         const float* __restrict__ bias, short* __restrict__ q,
                         short* __restrict__ k, short* __restrict__ vt) {
  __shared__ short Xl[128 * 136];
  __shared__ short Wl[64 * 136];
  int bx = blockIdx.x;
  int t = threadIdx.x;
  int lane = t & 63, w = t >> 6, l15 = lane & 15, quad = lane >> 4;
  if (bx < 1024) {
    // ---------- q,k part ----------
    int ot = bx & 3, nt = (bx >> 2) & 63, b = bx >> 8;
    for (int idx = t; idx < 64 * 16; idx += 256) {
      int row = idx >> 4, c8 = idx & 15;
      *(s8b*)&Xl[row * 136 + c8 * 8] =
          *(const s8b*)(xn + ((size_t)(b * NSP + nt * 64 + row)) * CCH + c8 * 8);
    }
    for (int idx = t; idx < 64 * 16; idx += 256) {
      int row = idx >> 4, c8 = idx & 15;
      const float* src = Wqkv + (size_t)(ot * 64 + row) * CCH + c8 * 8;
      s8b wv;
      #pragma unroll
      for (int j = 0; j < 8; ++j) wv[j] = f2bf(src[j]);
      *(s8b*)&Wl[row * 136 + c8 * 8] = wv;
    }
    __syncthreads();
    s8b a[4];
    #pragma unroll
    for (int kc = 0; kc < 4; ++kc)
      a[kc] = *(const s8b*)&Xl[(w * 16 + l15) * 136 + kc * 32 + quad * 8];
    #pragma unroll
    for (int o4 = 0; o4 < 4; ++o4) {
      f32x4 acc = {0.f, 0.f, 0.f, 0.f};
      #pragma unroll
      for (int kc = 0; kc < 4; ++kc) {
        s8b bw = *(const s8b*)&Wl[(o4 * 16 + l15) * 136 + kc * 32 + quad * 8];
        acc = mfma16(a[kc], bw, acc);
      }
      int obase = ot * 64 + o4 * 16;
      short* dst = (obase < 128) ? q : k;
      float mulf = (obase < 128) ? QSCALE : 1.0f;
      int oc = obase - ((obase < 128) ? 0 : 128) + l15;
      float bs = bias[obase + l15];
      #pragma unroll
      for (int r = 0; r < 4; ++r) {
        int n = nt * 64 + w * 16 + quad * 4 + r;
        dst[((size_t)(b * NSP + n)) * CCH + oc] = f2bf((acc[r] + bs) * mulf);
      }
    }
  } else {
    // ---------- v part ----------
    int vbx = bx - 1024;            // 256 = b(4) nt(32) ot(2)
    int ot = vbx & 1, nt = (vbx >> 1) & 31, b = vbx >> 6;
    for (int idx = t; idx < 128 * 16; idx += 256) {
      int row = idx >> 4, c8 = idx & 15;
      *(s8b*)&Xl[row * 136 + c8 * 8] =
          *(const s8b*)(xn + ((size_t)(b * NSP + nt * 128 + row)) * CCH + c8 * 8);
    }
    for (int idx = t; idx < 64 * 16; idx += 256) {
      int row = idx >> 4, c8 = idx & 15;
      const float* src = Wqkv + (size_t)(256 + ot * 64 + row) * CCH + c8 * 8;
      s8b wv;
      #pragma unroll
      for (int j = 0; j < 8; ++j) wv[j] = f2bf(src[j]);
      *(s8b*)&Wl[row * 136 + c8 * 8] = wv;
    }
    __syncthreads();
    s8b a[4];
    #pragma unroll
    for (int kc = 0; kc < 4; ++kc)
      a[kc] = *(const s8b*)&Wl[(w * 16 + l15) * 136 + kc * 32 + quad * 8];
    float bs[4];
    #pragma unroll
    for (int r = 0; r < 4; ++r) bs[r] = bias[256 + ot * 64 + w * 16 + quad * 4 + r];
    // permuted position within the 16-key chunk (see header comment)
    int ppos = 8 * ((l15 >> 2) & 1) + (l15 & 3) + 4 * (l15 >> 3);
    #pragma unroll
    for (int ntile = 0; ntile < 8; ++ntile) {
      f32x4 acc = {0.f, 0.f, 0.f, 0.f};
      #pragma unroll
      for (int kc = 0; kc < 4; ++kc) {
        s8b bx2 = *(const s8b*)&Xl[(ntile * 16 + l15) * 136 + kc * 32 + quad * 8];
        acc = mfma16(a[kc], bx2, acc);
      }
      int npos = nt * 128 + ntile * 16 + ppos;
      #pragma unroll
      for (int r = 0; r < 4; ++r) {
        int og = ot * 64 + w * 16 + quad * 4 + r;     // v channel
        vt[((size_t)(b * CCH + og)) * NSP + npos] = f2bf(acc[r] + bs[r]);
      }
    }
  }
}

// ---------------- Flash attention v9: 64 q-rows/wave, K/V fragment reuse x2 ----------------
// Grid 512 = kh(8 key-eighths) x b(4) x qt(16: 256-row tiles); 2 blocks/CU.
// Block 256 thr = 4 waves x 64 q-rows (2 sub-tiles of 32). Each K fragment
// ds_read feeds TWO independent S^T=K Q^T chains (qs=0/1); each V fragment
// feeds two PV chains -> 0.5 LDS reads per MFMA (was 1.0) and 2x MFMA ILP
// per wave. kh=8 keeps grid at 512 (2 blocks/CU) despite the bigger q-tile;
// cost is 8 O-partials merged in proj_gemm.
// C-layout of S^T (col=q-row, row=key) is directly a legal B-operand for
// O^T = V^T P^T after exp2+cvt_pk — V's in-chunk key permutation (done at
// qkv_gemm) makes the C-reg key order match the B k-slot order. No P LDS.
// l = per-lane scalar sum + shfl(32). K/V double-buffered via
// global_load_lds with XOR source swizzle (unchanged layouts).
__global__ __launch_bounds__(256, 2) void flash(const short* __restrict__ q,
                                                const short* __restrict__ k,
                                                const short* __restrict__ vt,
                                                short* __restrict__ Op,
                                                float* __restrict__ Lp) {
  int bx = blockIdx.x;
  int kh = bx & 7, b = (bx >> 3) & 3, qt = bx >> 5;
  __shared__ short lds[32768];       // 64KB total
  short* Kl = lds;                   // [2][64*128] 8-short groups XOR-swz by (key&15)
  short* Vl = lds + 16384;           // [2][128*64] 8-short groups XOR-swz by (ch&7)
  int t = threadIdx.x;
  int lane = t & 63, w = t >> 6;
  int l31 = lane & 31, h = lane >> 5;
  int x15 = l31 & 15, x7 = l31 & 7;
  const short* kbase = k + (size_t)b * NSP * CCH;
  const short* vbase = vt + (size_t)b * CCH * NSP;
  int kt0 = kh * 512;

  int krow_in_chunk = lane >> 4, kgrp = lane & 15;
  int vrow_in_chunk = lane >> 3, vgrp = lane & 7;

  // Q B-fragments, resident: qrow = qt*256 + w*64 + qs*32 + l31, c = h*8 + 16*kc
  s8b aq0[8], aq1[8];
  {
    const short* qp = q + ((size_t)(b * NSP + qt * 256 + w * 64 + l31)) * CCH + h * 8;
    #pragma unroll
    for (int kc = 0; kc < 8; ++kc) aq0[kc] = *(const s8b*)(qp + kc * 16);
    qp += (size_t)32 * CCH;
    #pragma unroll
    for (int kc = 0; kc < 8; ++kc) aq1[kc] = *(const s8b*)(qp + kc * 16);
  }
  f32x16 O0[4], O1[4];
  #pragma unroll
  for (int cg = 0; cg < 4; ++cg)
    #pragma unroll
    for (int r = 0; r < 16; ++r) { O0[cg][r] = 0.f; O1[cg][r] = 0.f; }
  float lsum0 = 0.f, lsum1 = 0.f;

  #define STAGE(buf_, key0_)                                                        \
    {                                                                               \
      const int key0v = (key0_);                                                    \
      _Pragma("unroll") for (int si = 0; si < 4; ++si) {                            \
        int c = w * 4 + si;                                                         \
        int rt = c * 4 + krow_in_chunk;                                             \
        async16(kbase + (size_t)(key0v + rt) * CCH + ((kgrp ^ (rt & 15)) * 8),      \
                Kl + (buf_) * 8192 + c * 512);                                      \
        int rc = c * 8 + vrow_in_chunk;                                             \
        async16(vbase + (size_t)rc * NSP + key0v + ((vgrp ^ (rc & 7)) * 8),         \
                Vl + (buf_) * 8192 + c * 512);                                      \
      }                                                                             \
    }

  STAGE(0, kt0)
  __syncthreads();

  for (int i = 0; i < 8; ++i) {
    int buf = i & 1;
    if (i < 7) STAGE(buf ^ 1, kt0 + (i + 1) * 64)
    int bo = buf * 8192;

    s8b pb0[4], pb1[4];
    #pragma unroll
    for (int tile = 0; tile < 2; ++tile) {
      // ---- S^T = K Q^T over one 32-key tile, two interleaved q-subtile chains ----
      f32x16 st0, st1;
      #pragma unroll
      for (int r = 0; r < 16; ++r) { st0[r] = 0.f; st1[r] = 0.f; }
      const short* kp = Kl + bo + (tile * 32 + l31) * 128;
      __builtin_amdgcn_s_setprio(1);
      #pragma unroll
      for (int kc = 0; kc < 8; ++kc) {
        s8b ak = *(const s8b*)&kp[((kc * 2 + h) ^ x15) * 8];
        st0 = mfma32(ak, aq0[kc], st0);
        st1 = mfma32(ak, aq1[kc], st1);
      }
      __builtin_amdgcn_s_setprio(0);
      // ---- p = exp2(s); l accumulate; C-regs straight into B-operands ----
      {
        float p[16];
        #pragma unroll
        for (int r = 0; r < 16; ++r) p[r] = fexp2(st0[r]);
        lsum0 += (((p[0] + p[1]) + (p[2] + p[3])) + ((p[4] + p[5]) + (p[6] + p[7]))) +
                 (((p[8] + p[9]) + (p[10] + p[11])) + ((p[12] + p[13]) + (p[14] + p[15])));
        pb0[tile * 2 + 0] = pack8(p[0], p[1], p[2], p[3], p[4], p[5], p[6], p[7]);
        pb0[tile * 2 + 1] = pack8(p[8], p[9], p[10], p[11], p[12], p[13], p[14], p[15]);
      }
      {
        float p[16];
        #pragma unroll
        for (int r = 0; r < 16; ++r) p[r] = fexp2(st1[r]);
        lsum1 += (((p[0] + p[1]) + (p[2] + p[3])) + ((p[4] + p[5]) + (p[6] + p[7]))) +
                 (((p[8] + p[9]) + (p[10] + p[11])) + ((p[12] + p[13]) + (p[14] + p[15])));
        pb1[tile * 2 + 0] = pack8(p[0], p[1], p[2], p[3], p[4], p[5], p[6], p[7]);
        pb1[tile * 2 + 1] = pack8(p[8], p[9], p[10], p[11], p[12], p[13], p[14], p[15]);
      }
    }
    // ---- O^T += V^T P^T: each V fragment feeds both q-subtiles ----
    __builtin_amdgcn_s_setprio(1);
    #pragma unroll
    for (int cg = 0; cg < 4; ++cg) {
      const short* vp = Vl + bo + (cg * 32 + l31) * 64;
      #pragma unroll
      for (int kc2 = 0; kc2 < 4; ++kc2) {
        s8b av = *(const s8b*)&vp[((kc2 * 2 + h) ^ x7) * 8];
        O0[cg] = mfma32(av, pb0[kc2], O0[cg]);
        O1[cg] = mfma32(av, pb1[kc2], O1[cg]);
      }
    }
    __builtin_amdgcn_s_setprio(0);
    __syncthreads();
  }

  // ---- l: combine the two half-lanes sharing a q-row ----
  lsum0 += __shfl_xor(lsum0, 32);
  lsum1 += __shfl_xor(lsum1, 32);

  // ---- epilogue: O^T -> LDS transpose (reuse whole LDS) -> coalesced global ----
  short* eb = lds + w * 8192;   // 64 rows x 128 ch bf16 per wave, groups swz by (n&7)
  #pragma unroll
  for (int cg = 0; cg < 4; ++cg)
    #pragma unroll
    for (int rp = 0; rp < 8; ++rp) {
      int r = rp * 2;
      int chlo = (r & 3) + 4 * h;          // within-8 offset (even)
      int chhi = cg * 4 + (r >> 2);        // 8-short group index
      *(unsigned*)&eb[l31 * 128 + ((chhi ^ x7)) * 8 + chlo] = cvtpk(O0[cg][r], O0[cg][r + 1]);
      *(unsigned*)&eb[4096 + l31 * 128 + ((chhi ^ x7)) * 8 + chlo] = cvtpk(O1[cg][r], O1[cg][r + 1]);
    }
  short* ob = Op + (size_t)kh * OPSTRIDE + ((size_t)(b * NSP + qt * 256)) * CCH;
  float* lp = Lp + kh * LPSTRIDE + b * NSP + qt * 256;
  if (lane < 32) { lp[w * 64 + l31] = lsum0; lp[w * 64 + 32 + l31] = lsum1; }
  __syncthreads();
  for (int idx = t; idx < 256 * 16; idx += 256) {
    int row = idx >> 4, c8 = idx & 15;
    int w2 = row >> 6, sub = (row >> 5) & 1, nl = row & 31;
    *(s8b*)(ob + (size_t)row * CCH + c8 * 8) =
        *(const s8b*)(lds + w2 * 8192 + sub * 4096 + nl * 128 + ((c8 ^ (nl & 7))) * 8);
  }
}

// ---------------- proj + bias + residual, merging the 8 kh partials ----------------
__global__ void proj_gemm(const short* __restrict__ Op, const float* __restrict__ Lp,
                          const float* __restrict__ Wp, const float* __restrict__ pbias,
                          const float* __restrict__ x, float* __restrict__ out) {
  int bx = blockIdx.x;            // 256 = b(4) nt(64)
  int nt = bx & 63, b = bx >> 6;
  __shared__ short Wl[128][136];
  int t = threadIdx.x;
  for (int idx = t; idx < 128 * 16; idx += 256) {
    int row = idx >> 4, c8 = idx & 15;
    const float* src = Wp + (size_t)row * CCH + c8 * 8;
    s8b wv;
    #pragma unroll
    for (int j = 0; j < 8; ++j) wv[j] = f2bf(src[j]);
    *(s8b*)&Wl[row][c8 * 8] = wv;
  }
  __syncthreads();
  int lane = t & 63, w = t >> 6, l15 = lane & 15, quad = lane >> 4;
  int row = nt * 64 + w * 16 + l15;             // this lane's ao row (m index)
  float lsum = 0.f;
  #pragma unroll
  for (int s = 0; s < KHN; ++s) lsum += Lp[(size_t)s * LPSTRIDE + b * NSP + row];
  float linv = 1.f / lsum;
  const short* ap = Op + ((size_t)(b * NSP + row)) * CCH + quad * 8;
  s8b bfr[4];
  #pragma unroll
  for (int kc = 0; kc < 4; ++kc) {
    float acc8[8];
    #pragma unroll
    for (int j = 0; j < 8; ++j) acc8[j] = 0.f;
    #pragma unroll
    for (int s = 0; s < KHN; ++s) {
      s8b tv = *(const s8b*)(ap + (size_t)s * OPSTRIDE + kc * 32);
      #pragma unroll
      for (int j = 0; j < 8; ++j) acc8[j] += bf2f(tv[j]);
    }
    #pragma unroll
    for (int j = 0; j < 8; ++j) bfr[kc][j] = f2bf(acc8[j] * linv);
  }
  #pragma unroll
  for (int cg = 0; cg < 8; ++cg) {
    f32x4 acc = {0.f, 0.f, 0.f, 0.f};
    #pragma unroll
    for (int kc = 0; kc < 4; ++kc) {
      s8b aw = *(const s8b*)&Wl[cg * 16 + l15][kc * 32 + quad * 8];
      acc = mfma16(aw, bfr[kc], acc);
    }
    #pragma unroll
    for (int r = 0; r < 4; ++r) {
      int co = cg * 16 + quad * 4 + r;
      int n = nt * 64 + w * 16 + l15;
      size_t off = ((size_t)(b * CCH + co)) * NSP + n;
      out[off] = x[off] + acc[r] + pbias[co];
    }
  }
}

extern "C" void kernel_launch(void* const* d_in, const int* in_sizes, int n_in,
                              void* d_out, int out_size, void* d_ws, size_t ws_size,
                              hipStream_t stream) {
  (void)in_sizes; (void)n_in; (void)out_size; (void)ws_size;
  const float* x    = (const float*)d_in[0];
  const float* gw   = (const float*)d_in[1];
  const float* gb   = (const float*)d_in[2];
  const float* Wqkv = (const float*)d_in[3];
  const float* bqkv = (const float*)d_in[4];
  const float* Wp   = (const float*)d_in[5];
  const float* bp   = (const float*)d_in[6];
  float* out = (float*)d_out;
  char* ws = (char*)d_ws;
  float* part = (float*)ws;                             // 512 floats
  short* xn    = (short*)(ws + 4096);
  short* q     = (short*)(ws + 4096 + 1ull * 4194304);
  short* k     = (short*)(ws + 4096 + 2ull * 4194304);
  short* vt    = (short*)(ws + 4096 + 3ull * 4194304);
  short* Opart = (short*)(ws + 4096 + 4ull * 4194304);  // 8 x 4MB bf16 partial O
  float* Lpart = (float*)(ws + 4096 + 12ull * 4194304); // 8 x 64KB fp32 partial l

  gn_stats<<<256, 256, 0, stream>>>(x, part);
  gn_apply<<<256, 256, 0, stream>>>(x, gw, gb, part, xn);
  qkv_gemm<<<1280, 256, 0, stream>>>(xn, Wqkv, bqkv, q, k, vt);
  flash<<<512, 256, 0, stream>>>(q, k, vt, Opart, Lpart);
  proj_gemm<<<256, 256, 0, stream>>>(Opart, Lpart, Wp, bp, x, out);
}

// Round 2
// 211.099 us; speedup vs baseline: 1.2955x; 1.2955x over previous
//
#include <hip/hip_runtime.h>

#define BATCH 4
#define CCH 128
#define NSP 4096
#define NGRP 8
#define GROUP_ELEMS 65536   // 16 ch * 4096
// ATT_SCALE * log2(e): folded into q at qkv_gemm so softmax is exp2(s)
#define QSCALE 0.12751744f
#define EPS_GN 1e-5f
#define KHN 8               // key-split count (8 partials)
#define OPSTRIDE 2097152    // 4*4096*128 shorts per kh partial
#define LPSTRIDE 16384      // 4*4096 floats per kh partial

typedef short s8b __attribute__((ext_vector_type(8)));
typedef float f32x4 __attribute__((ext_vector_type(4)));
typedef float f32x16 __attribute__((ext_vector_type(16)));

static __device__ __forceinline__ short f2bf(float f) {
  union { float f; unsigned u; } v; v.f = f;
  unsigned r = (v.u + 0x7FFFu + ((v.u >> 16) & 1u)) >> 16;
  return (short)r;
}

static __device__ __forceinline__ float bf2f(short s) {
  unsigned u = ((unsigned)(unsigned short)s) << 16;
  float f; __builtin_memcpy(&f, &u, 4); return f;
}

static __device__ __forceinline__ float fexp2(float x) {
#if __has_builtin(__builtin_amdgcn_exp2f)
  return __builtin_amdgcn_exp2f(x);
#else
  return exp2f(x);
#endif
}

// single-instruction pack of two f32 -> adjacent bf16 (RNE): lo=a, hi=b
static __device__ __forceinline__ unsigned cvtpk(float a, float b) {
  unsigned r;
  asm("v_cvt_pk_bf16_f32 %0, %1, %2" : "=v"(r) : "v"(a), "v"(b));
  return r;
}

static __device__ __forceinline__ s8b pack8(float a0, float a1, float a2, float a3,
                                            float a4, float a5, float a6, float a7) {
  union { unsigned u[4]; s8b v; } x;
  x.u[0] = cvtpk(a0, a1); x.u[1] = cvtpk(a2, a3);
  x.u[2] = cvtpk(a4, a5); x.u[3] = cvtpk(a6, a7);
  return x.v;
}

static __device__ __forceinline__ f32x4 mfma16(s8b a, s8b b, f32x4 c) {
  return __builtin_amdgcn_mfma_f32_16x16x32_bf16(a, b, c, 0, 0, 0);
}
static __device__ __forceinline__ f32x16 mfma32(s8b a, s8b b, f32x16 c) {
  return __builtin_amdgcn_mfma_f32_32x32x16_bf16(a, b, c, 0, 0, 0);
}

// async 16B global->LDS DMA; dest = wave-uniform base + lane*16
static __device__ __forceinline__ void async16(const void* g, void* l) {
  __builtin_amdgcn_global_load_lds(
      (const __attribute__((address_space(1))) void*)g,
      (__attribute__((address_space(3))) void*)l, 16, 0, 0);
}

// ---------------- GroupNorm pass 1: per-(b,g,chunk) partial sum/sumsq ----------------
__global__ void gn_stats(const float* __restrict__ x, float* __restrict__ part) {
  int bx = blockIdx.x;            // 256 = bg(32) * chunk(8)
  int ch = bx & 7, bg = bx >> 3;
  const float* base = x + (size_t)bg * GROUP_ELEMS + (size_t)ch * 8192;
  int t = threadIdx.x;
  float s = 0.f, ss = 0.f;
  #pragma unroll
  for (int i = 0; i < 8; ++i) {
    float4 v = *(const float4*)(base + i * 1024 + t * 4);
    s  += v.x + v.y + v.z + v.w;
    ss += v.x * v.x + v.y * v.y + v.z * v.z + v.w * v.w;
  }
  #pragma unroll
  for (int off = 1; off < 64; off <<= 1) {
    s  += __shfl_xor(s, off);
    ss += __shfl_xor(ss, off);
  }
  __shared__ float red[8];
  int w = t >> 6;
  if ((t & 63) == 0) { red[w * 2] = s; red[w * 2 + 1] = ss; }
  __syncthreads();
  if (t == 0) {
    part[bx * 2]     = red[0] + red[2] + red[4] + red[6];
    part[bx * 2 + 1] = red[1] + red[3] + red[5] + red[7];
  }
}

// ---------------- GroupNorm pass 2: reduce partials, normalize, write xn (b,n,c) bf16 ----------------
__global__ void gn_apply(const float* __restrict__ x, const float* __restrict__ gw,
                         const float* __restrict__ gb, const float* __restrict__ part,
                         short* __restrict__ xn) {
  int bx = blockIdx.x;            // 256 = b(4) g(8) ns(8)
  int ns = bx & 7, g = (bx >> 3) & 7, b = bx >> 6;
  int bg = b * NGRP + g;
  float s = 0.f, ss = 0.f;
  #pragma unroll
  for (int j = 0; j < 8; ++j) {
    s  += part[(bg * 8 + j) * 2];
    ss += part[(bg * 8 + j) * 2 + 1];
  }
  float mean = s * (1.f / GROUP_ELEMS);
  float var  = ss * (1.f / GROUP_ELEMS) - mean * mean;
  float inv  = rsqrtf(var + EPS_GN);
  int t = threadIdx.x;
  int cl = t & 15, n4 = t >> 4;
  int c = g * 16 + cl;
  float ga = gw[c] * inv;
  float be = gb[c] - mean * ga;
  const float* xr = x + (size_t)(b * CCH + c) * NSP;
  short* xo = xn + (size_t)b * NSP * CCH + c;
  #pragma unroll
  for (int i = 0; i < 8; ++i) {
    int n = ns * 512 + i * 64 + n4 * 4;
    float4 v = *(const float4*)(xr + n);
    xo[(size_t)(n + 0) * CCH] = f2bf(v.x * ga + be);
    xo[(size_t)(n + 1) * CCH] = f2bf(v.y * ga + be);
    xo[(size_t)(n + 2) * CCH] = f2bf(v.z * ga + be);
    xo[(size_t)(n + 3) * CCH] = f2bf(v.w * ga + be);
  }
}

// ---------------- Fused QKV: bx<1024 -> q,k (D[n][o]); else -> v (D[o][n], permuted key order) ----------------
// v is written TRANSPOSED (b,c,n); within each 16-key chunk the key order is
// permuted so flash's PV can consume P DIRECTLY from the S^T MFMA C-registers:
// orig key kk (0..15) -> pos = 8*((kk>>2)&1) + (kk&3) + 4*(kk>>3)
__global__ void qkv_gemm(const short* __restrict__ xn, const float* __restrict__ Wqkv,
                         const float* __restrict__ bias, short* __restrict__ q,
                         short* __restrict__ k, short* __restrict__ vt) {
  __shared__ short Xl[128 * 136];
  __shared__ short Wl[64 * 136];
  int bx = blockIdx.x;
  int t = threadIdx.x;
  int lane = t & 63, w = t >> 6, l15 = lane & 15, quad = lane >> 4;
  if (bx < 1024) {
    // ---------- q,k part ----------
    int ot = bx & 3, nt = (bx >> 2) & 63, b = bx >> 8;
    for (int idx = t; idx < 64 * 16; idx += 256) {
      int row = idx >> 4, c8 = idx & 15;
      *(s8b*)&Xl[row * 136 + c8 * 8] =
          *(const s8b*)(xn + ((size_t)(b * NSP + nt * 64 + row)) * CCH + c8 * 8);
    }
    for (int idx = t; idx < 64 * 16; idx += 256) {
      int row = idx >> 4, c8 = idx & 15;
      const float* src = Wqkv + (size_t)(ot * 64 + row) * CCH + c8 * 8;
      s8b wv;
      #pragma unroll
      for (int j = 0; j < 8; ++j) wv[j] = f2bf(src[j]);
      *(s8b*)&Wl[row * 136 + c8 * 8] = wv;
    }
    __syncthreads();
    s8b a[4];
    #pragma unroll
    for (int kc = 0; kc < 4; ++kc)
      a[kc] = *(const s8b*)&Xl[(w * 16 + l15) * 136 + kc * 32 + quad * 8];
    #pragma unroll
    for (int o4 = 0; o4 < 4; ++o4) {
      f32x4 acc = {0.f, 0.f, 0.f, 0.f};
      #pragma unroll
      for (int kc = 0; kc < 4; ++kc) {
        s8b bw = *(const s8b*)&Wl[(o4 * 16 + l15) * 136 + kc * 32 + quad * 8];
        acc = mfma16(a[kc], bw, acc);
      }
      int obase = ot * 64 + o4 * 16;
      short* dst = (obase < 128) ? q : k;
      float mulf = (obase < 128) ? QSCALE : 1.0f;
      int oc = obase - ((obase < 128) ? 0 : 128) + l15;
      float bs = bias[obase + l15];
      #pragma unroll
      for (int r = 0; r < 4; ++r) {
        int n = nt * 64 + w * 16 + quad * 4 + r;
        dst[((size_t)(b * NSP + n)) * CCH + oc] = f2bf((acc[r] + bs) * mulf);
      }
    }
  } else {
    // ---------- v part ----------
    int vbx = bx - 1024;            // 256 = b(4) nt(32) ot(2)
    int ot = vbx & 1, nt = (vbx >> 1) & 31, b = vbx >> 6;
    for (int idx = t; idx < 128 * 16; idx += 256) {
      int row = idx >> 4, c8 = idx & 15;
      *(s8b*)&Xl[row * 136 + c8 * 8] =
          *(const s8b*)(xn + ((size_t)(b * NSP + nt * 128 + row)) * CCH + c8 * 8);
    }
    for (int idx = t; idx < 64 * 16; idx += 256) {
      int row = idx >> 4, c8 = idx & 15;
      const float* src = Wqkv + (size_t)(256 + ot * 64 + row) * CCH + c8 * 8;
      s8b wv;
      #pragma unroll
      for (int j = 0; j < 8; ++j) wv[j] = f2bf(src[j]);
      *(s8b*)&Wl[row * 136 + c8 * 8] = wv;
    }
    __syncthreads();
    s8b a[4];
    #pragma unroll
    for (int kc = 0; kc < 4; ++kc)
      a[kc] = *(const s8b*)&Wl[(w * 16 + l15) * 136 + kc * 32 + quad * 8];
    float bs[4];
    #pragma unroll
    for (int r = 0; r < 4; ++r) bs[r] = bias[256 + ot * 64 + w * 16 + quad * 4 + r];
    // permuted position within the 16-key chunk (see header comment)
    int ppos = 8 * ((l15 >> 2) & 1) + (l15 & 3) + 4 * (l15 >> 3);
    #pragma unroll
    for (int ntile = 0; ntile < 8; ++ntile) {
      f32x4 acc = {0.f, 0.f, 0.f, 0.f};
      #pragma unroll
      for (int kc = 0; kc < 4; ++kc) {
        s8b bx2 = *(const s8b*)&Xl[(ntile * 16 + l15) * 136 + kc * 32 + quad * 8];
        acc = mfma16(a[kc], bx2, acc);
      }
      int npos = nt * 128 + ntile * 16 + ppos;
      #pragma unroll
      for (int r = 0; r < 4; ++r) {
        int og = ot * 64 + w * 16 + quad * 4 + r;     // v channel
        vt[((size_t)(b * CCH + og)) * NSP + npos] = f2bf(acc[r] + bs[r]);
      }
    }
  }
}

// ---------------- Flash attention v10: 8-wave blocks, 4 waves/SIMD ----------------
// Grid 512 = kh(8 key-eighths) x b(4) x qt(16: 256-row tiles); 512 threads =
// 8 waves x 32 q-rows. Per-wave structure identical to the proven v8 kernel
// (aq[8] resident, O[4], 104 VGPR — no spills); the 8 waves SHARE the same
// 64KB double-buffered K/V tiles, so LDS/block is unchanged -> still
// 2 blocks/CU but now 16 waves/CU = 4 waves/SIMD (was 2): latency holes in
// the MFMA/VALU phases get filled by sibling waves instead of stalling.
// kh=8 keeps the grid at 512; cost is 8 O-partials merged in proj_gemm.
// C-layout of S^T (col=q-row, row=key) is directly a legal B-operand for
// O^T = V^T P^T after exp2+cvt_pk — V's in-chunk key permutation (done at
// qkv_gemm) makes the C-reg key order match the B k-slot order. No P LDS.
// l = per-lane scalar sum + shfl(32). K/V double-buffered via
// global_load_lds with XOR source swizzle (unchanged layouts).
__global__ __launch_bounds__(512, 4) void flash(const short* __restrict__ q,
                                                const short* __restrict__ k,
                                                const short* __restrict__ vt,
                                                short* __restrict__ Op,
                                                float* __restrict__ Lp) {
  int bx = blockIdx.x;
  int kh = bx & 7, b = (bx >> 3) & 3, qt = bx >> 5;
  __shared__ short lds[32768];       // 64KB total
  short* Kl = lds;                   // [2][64*128] 8-short groups XOR-swz by (key&15)
  short* Vl = lds + 16384;           // [2][128*64] 8-short groups XOR-swz by (ch&7)
  int t = threadIdx.x;
  int lane = t & 63, w = t >> 6;     // w in 0..7
  int l31 = lane & 31, h = lane >> 5;
  int x15 = l31 & 15, x7 = l31 & 7;
  const short* kbase = k + (size_t)b * NSP * CCH;
  const short* vbase = vt + (size_t)b * CCH * NSP;
  int kt0 = kh * 512;

  int krow_in_chunk = lane >> 4, kgrp = lane & 15;
  int vrow_in_chunk = lane >> 3, vgrp = lane & 7;

  // Q B-fragments, resident: qrow = qt*256 + w*32 + l31, c = h*8 + 16*kc
  s8b aq[8];
  {
    const short* qp = q + ((size_t)(b * NSP + qt * 256 + w * 32 + l31)) * CCH + h * 8;
    #pragma unroll
    for (int kc = 0; kc < 8; ++kc) aq[kc] = *(const s8b*)(qp + kc * 16);
  }
  f32x16 O[4];
  #pragma unroll
  for (int cg = 0; cg < 4; ++cg)
    #pragma unroll
    for (int r = 0; r < 16; ++r) O[cg][r] = 0.f;
  float lsum = 0.f;

  // 8 waves x 2 si x (1 K + 1 V) x 1KB = 32KB staged per tile
  #define STAGE(buf_, key0_)                                                        \
    {                                                                               \
      const int key0v = (key0_);                                                    \
      _Pragma("unroll") for (int si = 0; si < 2; ++si) {                            \
        int c = w * 2 + si;                                                         \
        int rt = c * 4 + krow_in_chunk;                                             \
        async16(kbase + (size_t)(key0v + rt) * CCH + ((kgrp ^ (rt & 15)) * 8),      \
                Kl + (buf_) * 8192 + c * 512);                                      \
        int rc = c * 8 + vrow_in_chunk;                                             \
        async16(vbase + (size_t)rc * NSP + key0v + ((vgrp ^ (rc & 7)) * 8),         \
                Vl + (buf_) * 8192 + c * 512);                                      \
      }                                                                             \
    }

  STAGE(0, kt0)
  __syncthreads();

  for (int i = 0; i < 8; ++i) {
    int buf = i & 1;
    if (i < 7) STAGE(buf ^ 1, kt0 + (i + 1) * 64)
    int bo = buf * 8192;

    s8b pb[4];
    #pragma unroll
    for (int tile = 0; tile < 2; ++tile) {
      // ---- S^T = K Q^T over one 32-key tile ----
      f32x16 st;
      #pragma unroll
      for (int r = 0; r < 16; ++r) st[r] = 0.f;
      const short* kp = Kl + bo + (tile * 32 + l31) * 128;
      __builtin_amdgcn_s_setprio(1);
      #pragma unroll
      for (int kc = 0; kc < 8; ++kc) {
        s8b ak = *(const s8b*)&kp[((kc * 2 + h) ^ x15) * 8];
        st = mfma32(ak, aq[kc], st);
      }
      __builtin_amdgcn_s_setprio(0);
      // ---- p = exp2(s); l accumulate; pack C-regs straight into B-operands ----
      float pp[16];
      #pragma unroll
      for (int r = 0; r < 16; ++r) pp[r] = fexp2(st[r]);
      lsum += (((pp[0] + pp[1]) + (pp[2] + pp[3])) + ((pp[4] + pp[5]) + (pp[6] + pp[7]))) +
              (((pp[8] + pp[9]) + (pp[10] + pp[11])) + ((pp[12] + pp[13]) + (pp[14] + pp[15])));
      pb[tile * 2 + 0] = pack8(pp[0], pp[1], pp[2], pp[3], pp[4], pp[5], pp[6], pp[7]);
      pb[tile * 2 + 1] = pack8(pp[8], pp[9], pp[10], pp[11], pp[12], pp[13], pp[14], pp[15]);
    }
    // ---- O^T += V^T P^T ----
    __builtin_amdgcn_s_setprio(1);
    #pragma unroll
    for (int cg = 0; cg < 4; ++cg) {
      const short* vp = Vl + bo + (cg * 32 + l31) * 64;
      #pragma unroll
      for (int kc2 = 0; kc2 < 4; ++kc2) {
        s8b av = *(const s8b*)&vp[((kc2 * 2 + h) ^ x7) * 8];
        O[cg] = mfma32(av, pb[kc2], O[cg]);
      }
    }
    __builtin_amdgcn_s_setprio(0);
    __syncthreads();
  }

  // ---- l: combine the two half-lanes sharing a q-row ----
  lsum += __shfl_xor(lsum, 32);

  // ---- epilogue: O^T -> LDS transpose (reuse whole LDS) -> coalesced global ----
  short* eb = lds + w * 4096;   // 32 rows x 128 ch bf16 per wave, groups swz by (n&7)
  #pragma unroll
  for (int cg = 0; cg < 4; ++cg)
    #pragma unroll
    for (int rp = 0; rp < 8; ++rp) {
      int r = rp * 2;
      int chlo = (r & 3) + 4 * h;          // within-8 offset (even)
      int chhi = cg * 4 + (r >> 2);        // 8-short group index
      *(unsigned*)&eb[l31 * 128 + ((chhi ^ x7)) * 8 + chlo] = cvtpk(O[cg][r], O[cg][r + 1]);
    }
  short* ob = Op + (size_t)kh * OPSTRIDE + ((size_t)(b * NSP + qt * 256)) * CCH;
  float* lp = Lp + kh * LPSTRIDE + b * NSP + qt * 256;
  if (lane < 32) lp[w * 32 + l31] = lsum;
  __syncthreads();
  for (int idx = t; idx < 256 * 16; idx += 512) {
    int row = idx >> 4, c8 = idx & 15;
    int w2 = row >> 5, nl = row & 31;
    *(s8b*)(ob + (size_t)row * CCH + c8 * 8) =
        *(const s8b*)(lds + w2 * 4096 + nl * 128 + ((c8 ^ (nl & 7))) * 8);
  }
}

// ---------------- proj + bias + residual, merging the 8 kh partials ----------------
__global__ void proj_gemm(const short* __restrict__ Op, const float* __restrict__ Lp,
                          const float* __restrict__ Wp, const float* __restrict__ pbias,
                          const float* __restrict__ x, float* __restrict__ out) {
  int bx = blockIdx.x;            // 256 = b(4) nt(64)
  int nt = bx & 63, b = bx >> 6;
  __shared__ short Wl[128][136];
  int t = threadIdx.x;
  for (int idx = t; idx < 128 * 16; idx += 256) {
    int row = idx >> 4, c8 = idx & 15;
    const float* src = Wp + (size_t)row * CCH + c8 * 8;
    s8b wv;
    #pragma unroll
    for (int j = 0; j < 8; ++j) wv[j] = f2bf(src[j]);
    *(s8b*)&Wl[row][c8 * 8] = wv;
  }
  __syncthreads();
  int lane = t & 63, w = t >> 6, l15 = lane & 15, quad = lane >> 4;
  int row = nt * 64 + w * 16 + l15;             // this lane's ao row (m index)
  float lsum = 0.f;
  #pragma unroll
  for (int s = 0; s < KHN; ++s) lsum += Lp[(size_t)s * LPSTRIDE + b * NSP + row];
  float linv = 1.f / lsum;
  const short* ap = Op + ((size_t)(b * NSP + row)) * CCH + quad * 8;
  s8b bfr[4];
  #pragma unroll
  for (int kc = 0; kc < 4; ++kc) {
    float acc8[8];
    #pragma unroll
    for (int j = 0; j < 8; ++j) acc8[j] = 0.f;
    #pragma unroll
    for (int s = 0; s < KHN; ++s) {
      s8b tv = *(const s8b*)(ap + (size_t)s * OPSTRIDE + kc * 32);
      #pragma unroll
      for (int j = 0; j < 8; ++j) acc8[j] += bf2f(tv[j]);
    }
    #pragma unroll
    for (int j = 0; j < 8; ++j) bfr[kc][j] = f2bf(acc8[j] * linv);
  }
  #pragma unroll
  for (int cg = 0; cg < 8; ++cg) {
    f32x4 acc = {0.f, 0.f, 0.f, 0.f};
    #pragma unroll
    for (int kc = 0; kc < 4; ++kc) {
      s8b aw = *(const s8b*)&Wl[cg * 16 + l15][kc * 32 + quad * 8];
      acc = mfma16(aw, bfr[kc], acc);
    }
    #pragma unroll
    for (int r = 0; r < 4; ++r) {
      int co = cg * 16 + quad * 4 + r;
      int n = nt * 64 + w * 16 + l15;
      size_t off = ((size_t)(b * CCH + co)) * NSP + n;
      out[off] = x[off] + acc[r] + pbias[co];
    }
  }
}

extern "C" void kernel_launch(void* const* d_in, const int* in_sizes, int n_in,
                              void* d_out, int out_size, void* d_ws, size_t ws_size,
                              hipStream_t stream) {
  (void)in_sizes; (void)n_in; (void)out_size; (void)ws_size;
  const float* x    = (const float*)d_in[0];
  const float* gw   = (const float*)d_in[1];
  const float* gb   = (const float*)d_in[2];
  const float* Wqkv = (const float*)d_in[3];
  const float* bqkv = (const float*)d_in[4];
  const float* Wp   = (const float*)d_in[5];
  const float* bp   = (const float*)d_in[6];
  float* out = (float*)d_out;
  char* ws = (char*)d_ws;
  float* part = (float*)ws;                             // 512 floats
  short* xn    = (short*)(ws + 4096);
  short* q     = (short*)(ws + 4096 + 1ull * 4194304);
  short* k     = (short*)(ws + 4096 + 2ull * 4194304);
  short* vt    = (short*)(ws + 4096 + 3ull * 4194304);
  short* Opart = (short*)(ws + 4096 + 4ull * 4194304);  // 8 x 4MB bf16 partial O
  float* Lpart = (float*)(ws + 4096 + 12ull * 4194304); // 8 x 64KB fp32 partial l

  gn_stats<<<256, 256, 0, stream>>>(x, part);
  gn_apply<<<256, 256, 0, stream>>>(x, gw, gb, part, xn);
  qkv_gemm<<<1280, 256, 0, stream>>>(xn, Wqkv, bqkv, q, k, vt);
  flash<<<512, 512, 0, stream>>>(q, k, vt, Opart, Lpart);
  proj_gemm<<<256, 256, 0, stream>>>(Opart, Lpart, Wp, bp, x, out);
}

// Round 3
// 134.413 us; speedup vs baseline: 2.0346x; 1.5705x over previous
//
#include <hip/hip_runtime.h>

#define BATCH 4
#define CCH 128
#define NSP 4096
#define NGRP 8
#define GROUP_ELEMS 65536   // 16 ch * 4096
// ATT_SCALE * log2(e): folded into q at qkv_gemm so softmax is exp2(s)
#define QSCALE 0.12751744f
#define EPS_GN 1e-5f
#define KHN 4               // key-split count (4 partials)
#define OPSTRIDE 2097152    // 4*4096*128 shorts per kh partial
#define LPSTRIDE 16384      // 4*4096 floats per kh partial

typedef short s8b __attribute__((ext_vector_type(8)));
typedef float f32x4 __attribute__((ext_vector_type(4)));
typedef float f32x16 __attribute__((ext_vector_type(16)));

static __device__ __forceinline__ short f2bf(float f) {
  union { float f; unsigned u; } v; v.f = f;
  unsigned r = (v.u + 0x7FFFu + ((v.u >> 16) & 1u)) >> 16;
  return (short)r;
}

static __device__ __forceinline__ float bf2f(short s) {
  unsigned u = ((unsigned)(unsigned short)s) << 16;
  float f; __builtin_memcpy(&f, &u, 4); return f;
}

static __device__ __forceinline__ float fexp2(float x) {
#if __has_builtin(__builtin_amdgcn_exp2f)
  return __builtin_amdgcn_exp2f(x);
#else
  return exp2f(x);
#endif
}

// single-instruction pack of two f32 -> adjacent bf16 (RNE): lo=a, hi=b
static __device__ __forceinline__ unsigned cvtpk(float a, float b) {
  unsigned r;
  asm("v_cvt_pk_bf16_f32 %0, %1, %2" : "=v"(r) : "v"(a), "v"(b));
  return r;
}

static __device__ __forceinline__ s8b pack8(float a0, float a1, float a2, float a3,
                                            float a4, float a5, float a6, float a7) {
  union { unsigned u[4]; s8b v; } x;
  x.u[0] = cvtpk(a0, a1); x.u[1] = cvtpk(a2, a3);
  x.u[2] = cvtpk(a4, a5); x.u[3] = cvtpk(a6, a7);
  return x.v;
}

static __device__ __forceinline__ f32x4 mfma16(s8b a, s8b b, f32x4 c) {
  return __builtin_amdgcn_mfma_f32_16x16x32_bf16(a, b, c, 0, 0, 0);
}
static __device__ __forceinline__ f32x16 mfma32(s8b a, s8b b, f32x16 c) {
  return __builtin_amdgcn_mfma_f32_32x32x16_bf16(a, b, c, 0, 0, 0);
}

// async 16B global->LDS DMA; dest = wave-uniform base + lane*16
static __device__ __forceinline__ void async16(const void* g, void* l) {
  __builtin_amdgcn_global_load_lds(
      (const __attribute__((address_space(1))) void*)g,
      (__attribute__((address_space(3))) void*)l, 16, 0, 0);
}

// ---------------- GroupNorm pass 1: per-(b,g,chunk) partial sum/sumsq ----------------
__global__ void gn_stats(const float* __restrict__ x, float* __restrict__ part) {
  int bx = blockIdx.x;            // 256 = bg(32) * chunk(8)
  int ch = bx & 7, bg = bx >> 3;
  const float* base = x + (size_t)bg * GROUP_ELEMS + (size_t)ch * 8192;
  int t = threadIdx.x;
  float s = 0.f, ss = 0.f;
  #pragma unroll
  for (int i = 0; i < 8; ++i) {
    float4 v = *(const float4*)(base + i * 1024 + t * 4);
    s  += v.x + v.y + v.z + v.w;
    ss += v.x * v.x + v.y * v.y + v.z * v.z + v.w * v.w;
  }
  #pragma unroll
  for (int off = 1; off < 64; off <<= 1) {
    s  += __shfl_xor(s, off);
    ss += __shfl_xor(ss, off);
  }
  __shared__ float red[8];
  int w = t >> 6;
  if ((t & 63) == 0) { red[w * 2] = s; red[w * 2 + 1] = ss; }
  __syncthreads();
  if (t == 0) {
    part[bx * 2]     = red[0] + red[2] + red[4] + red[6];
    part[bx * 2 + 1] = red[1] + red[3] + red[5] + red[7];
  }
}

// ---------------- GroupNorm pass 2: reduce partials, normalize, write xn (b,n,c) bf16 ----------------
__global__ void gn_apply(const float* __restrict__ x, const float* __restrict__ gw,
                         const float* __restrict__ gb, const float* __restrict__ part,
                         short* __restrict__ xn) {
  int bx = blockIdx.x;            // 256 = b(4) g(8) ns(8)
  int ns = bx & 7, g = (bx >> 3) & 7, b = bx >> 6;
  int bg = b * NGRP + g;
  float s = 0.f, ss = 0.f;
  #pragma unroll
  for (int j = 0; j < 8; ++j) {
    s  += part[(bg * 8 + j) * 2];
    ss += part[(bg * 8 + j) * 2 + 1];
  }
  float mean = s * (1.f / GROUP_ELEMS);
  float var  = ss * (1.f / GROUP_ELEMS) - mean * mean;
  float inv  = rsqrtf(var + EPS_GN);
  int t = threadIdx.x;
  int cl = t & 15, n4 = t >> 4;
  int c = g * 16 + cl;
  float ga = gw[c] * inv;
  float be = gb[c] - mean * ga;
  const float* xr = x + (size_t)(b * CCH + c) * NSP;
  short* xo = xn + (size_t)b * NSP * CCH + c;
  #pragma unroll
  for (int i = 0; i < 8; ++i) {
    int n = ns * 512 + i * 64 + n4 * 4;
    float4 v = *(const float4*)(xr + n);
    xo[(size_t)(n + 0) * CCH] = f2bf(v.x * ga + be);
    xo[(size_t)(n + 1) * CCH] = f2bf(v.y * ga + be);
    xo[(size_t)(n + 2) * CCH] = f2bf(v.z * ga + be);
    xo[(size_t)(n + 3) * CCH] = f2bf(v.w * ga + be);
  }
}

// ---------------- Fused QKV: bx<1024 -> q,k (D[n][o]); else -> v (D[o][n], permuted key order) ----------------
// v is written TRANSPOSED (b,c,n); within each 16-key chunk the key order is
// permuted so flash's PV can consume P DIRECTLY from the S^T MFMA C-registers:
// orig key kk (0..15) -> pos = 8*((kk>>2)&1) + (kk&3) + 4*(kk>>3)
__global__ void qkv_gemm(const short* __restrict__ xn, const float* __restrict__ Wqkv,
                         const float* __restrict__ bias, short* __restrict__ q,
                         short* __restrict__ k, short* __restrict__ vt) {
  __shared__ short Xl[128 * 136];
  __shared__ short Wl[64 * 136];
  int bx = blockIdx.x;
  int t = threadIdx.x;
  int lane = t & 63, w = t >> 6, l15 = lane & 15, quad = lane >> 4;
  if (bx < 1024) {
    // ---------- q,k part ----------
    int ot = bx & 3, nt = (bx >> 2) & 63, b = bx >> 8;
    for (int idx = t; idx < 64 * 16; idx += 256) {
      int row = idx >> 4, c8 = idx & 15;
      *(s8b*)&Xl[row * 136 + c8 * 8] =
          *(const s8b*)(xn + ((size_t)(b * NSP + nt * 64 + row)) * CCH + c8 * 8);
    }
    for (int idx = t; idx < 64 * 16; idx += 256) {
      int row = idx >> 4, c8 = idx & 15;
      const float* src = Wqkv + (size_t)(ot * 64 + row) * CCH + c8 * 8;
      s8b wv;
      #pragma unroll
      for (int j = 0; j < 8; ++j) wv[j] = f2bf(src[j]);
      *(s8b*)&Wl[row * 136 + c8 * 8] = wv;
    }
    __syncthreads();
    s8b a[4];
    #pragma unroll
    for (int kc = 0; kc < 4; ++kc)
      a[kc] = *(const s8b*)&Xl[(w * 16 + l15) * 136 + kc * 32 + quad * 8];
    #pragma unroll
    for (int o4 = 0; o4 < 4; ++o4) {
      f32x4 acc = {0.f, 0.f, 0.f, 0.f};
      #pragma unroll
      for (int kc = 0; kc < 4; ++kc) {
        s8b bw = *(const s8b*)&Wl[(o4 * 16 + l15) * 136 + kc * 32 + quad * 8];
        acc = mfma16(a[kc], bw, acc);
      }
      int obase = ot * 64 + o4 * 16;
      short* dst = (obase < 128) ? q : k;
      float mulf = (obase < 128) ? QSCALE : 1.0f;
      int oc = obase - ((obase < 128) ? 0 : 128) + l15;
      float bs = bias[obase + l15];
      #pragma unroll
      for (int r = 0; r < 4; ++r) {
        int n = nt * 64 + w * 16 + quad * 4 + r;
        dst[((size_t)(b * NSP + n)) * CCH + oc] = f2bf((acc[r] + bs) * mulf);
      }
    }
  } else {
    // ---------- v part ----------
    int vbx = bx - 1024;            // 256 = b(4) nt(32) ot(2)
    int ot = vbx & 1, nt = (vbx >> 1) & 31, b = vbx >> 6;
    for (int idx = t; idx < 128 * 16; idx += 256) {
      int row = idx >> 4, c8 = idx & 15;
      *(s8b*)&Xl[row * 136 + c8 * 8] =
          *(const s8b*)(xn + ((size_t)(b * NSP + nt * 128 + row)) * CCH + c8 * 8);
    }
    for (int idx = t; idx < 64 * 16; idx += 256) {
      int row = idx >> 4, c8 = idx & 15;
      const float* src = Wqkv + (size_t)(256 + ot * 64 + row) * CCH + c8 * 8;
      s8b wv;
      #pragma unroll
      for (int j = 0; j < 8; ++j) wv[j] = f2bf(src[j]);
      *(s8b*)&Wl[row * 136 + c8 * 8] = wv;
    }
    __syncthreads();
    s8b a[4];
    #pragma unroll
    for (int kc = 0; kc < 4; ++kc)
      a[kc] = *(const s8b*)&Wl[(w * 16 + l15) * 136 + kc * 32 + quad * 8];
    float bs[4];
    #pragma unroll
    for (int r = 0; r < 4; ++r) bs[r] = bias[256 + ot * 64 + w * 16 + quad * 4 + r];
    // permuted position within the 16-key chunk (see header comment)
    int ppos = 8 * ((l15 >> 2) & 1) + (l15 & 3) + 4 * (l15 >> 3);
    #pragma unroll
    for (int ntile = 0; ntile < 8; ++ntile) {
      f32x4 acc = {0.f, 0.f, 0.f, 0.f};
      #pragma unroll
      for (int kc = 0; kc < 4; ++kc) {
        s8b bx2 = *(const s8b*)&Xl[(ntile * 16 + l15) * 136 + kc * 32 + quad * 8];
        acc = mfma16(a[kc], bx2, acc);
      }
      int npos = nt * 128 + ntile * 16 + ppos;
      #pragma unroll
      for (int r = 0; r < 4; ++r) {
        int og = ot * 64 + w * 16 + quad * 4 + r;     // v channel
        vt[((size_t)(b * CCH + og)) * NSP + npos] = f2bf(acc[r] + bs[r]);
      }
    }
  }
}

// ---------------- Flash attention v11: v8 structure + interleaved dual S^T chains ----------------
// Grid 512 = qt(32: 128-row tiles) x b(4) x kh(4 key quarters); 2 blocks/CU
// (LDS-limited: 2x64KB; VGPR ~200/256 cap at bounds(256,2) — NO spill; the
// 512-thr/4-wave-SIMD variants both spilled catastrophically, see R1/R2).
// Block 256 thr = 4 waves x 32 q-rows. Computes S^T = K Q^T (A=K, B=Q) so the
// C-layout (col=q-row, row=key) is directly a legal B-operand for
// O^T = V^T P^T after exp2+cvt_pk — V's in-chunk key permutation (done at
// qkv_gemm) makes the C-reg key order match the B k-slot order. No P LDS.
// NEW vs v8: the two independent 32-key tiles' S^T chains are computed in ONE
// interleaved 16-MFMA cluster (st0/st1 both live, +16 VGPR) -> 2x chain ILP
// in the MFMA pipe, and one merged exp/pack VALU cluster -> coarser
// MFMA/VALU alternation across sibling waves (setprio arbitrates).
// l = per-lane scalar sum (a lane's whole C column is ONE q-row) + shfl(32).
// K/V double-buffered via global_load_lds, XOR source swizzle.
__global__ __launch_bounds__(256, 2) void flash(const short* __restrict__ q,
                                                const short* __restrict__ k,
                                                const short* __restrict__ vt,
                                                short* __restrict__ Op,
                                                float* __restrict__ Lp) {
  int bx = blockIdx.x;
  int kh = bx & 3, b = (bx >> 2) & 3, qt = bx >> 4;
  __shared__ short Kl[2][64 * 128];   // [key][ch], 8-short groups XOR-swizzled by (key&15)
  __shared__ short Vl[2][128 * 64];   // [ch][pos], 8-short groups XOR-swizzled by (ch&7)
  int t = threadIdx.x;
  int lane = t & 63, w = t >> 6;
  int l31 = lane & 31, h = lane >> 5;
  int x15 = l31 & 15, x7 = l31 & 7;
  const short* kbase = k + (size_t)b * NSP * CCH;
  const short* vbase = vt + (size_t)b * CCH * NSP;
  int kt0 = kh * 1024;

  int krow_in_chunk = lane >> 4, kgrp = lane & 15;
  int vrow_in_chunk = lane >> 3, vgrp = lane & 7;

  // Q B-fragments, resident: qrow = qt*128 + w*32 + l31, c = h*8 + 16*kc
  s8b aq[8];
  {
    const short* qp = q + ((size_t)(b * NSP + qt * 128 + w * 32 + l31)) * CCH + h * 8;
    #pragma unroll
    for (int kc = 0; kc < 8; ++kc) aq[kc] = *(const s8b*)(qp + kc * 16);
  }
  f32x16 O[4];
  #pragma unroll
  for (int cg = 0; cg < 4; ++cg)
    #pragma unroll
    for (int r = 0; r < 16; ++r) O[cg][r] = 0.f;
  float lsum = 0.f;

  #define STAGE(buf_, key0_)                                                        \
    {                                                                               \
      const int key0v = (key0_);                                                    \
      _Pragma("unroll") for (int si = 0; si < 4; ++si) {                            \
        int c = w * 4 + si;                                                         \
        int rt = c * 4 + krow_in_chunk;                                             \
        async16(kbase + (size_t)(key0v + rt) * CCH + ((kgrp ^ (rt & 15)) * 8),      \
                &Kl[buf_][c * 512]);                                                \
        int rc = c * 8 + vrow_in_chunk;                                             \
        async16(vbase + (size_t)rc * NSP + key0v + ((vgrp ^ (rc & 7)) * 8),         \
                &Vl[buf_][c * 512]);                                                \
      }                                                                             \
    }

  STAGE(0, kt0)
  __syncthreads();

  for (int i = 0; i < 16; ++i) {
    int buf = i & 1;
    if (i < 15) STAGE(buf ^ 1, kt0 + (i + 1) * 64)

    // ---- S^T = K Q^T over both 32-key tiles, two interleaved chains ----
    f32x16 st0, st1;
    #pragma unroll
    for (int r = 0; r < 16; ++r) { st0[r] = 0.f; st1[r] = 0.f; }
    const short* kp0 = &Kl[buf][(l31) * 128];
    const short* kp1 = &Kl[buf][(32 + l31) * 128];
    __builtin_amdgcn_s_setprio(1);
    #pragma unroll
    for (int kc = 0; kc < 8; ++kc) {
      int go = ((kc * 2 + h) ^ x15) * 8;
      s8b ak0 = *(const s8b*)&kp0[go];
      s8b ak1 = *(const s8b*)&kp1[go];
      st0 = mfma32(ak0, aq[kc], st0);
      st1 = mfma32(ak1, aq[kc], st1);
    }
    __builtin_amdgcn_s_setprio(0);

    // ---- p = exp2(s); l accumulate; pack C-regs straight into B-operands ----
    s8b pb[4];
    {
      float pp[16];
      #pragma unroll
      for (int r = 0; r < 16; ++r) pp[r] = fexp2(st0[r]);
      lsum += (((pp[0] + pp[1]) + (pp[2] + pp[3])) + ((pp[4] + pp[5]) + (pp[6] + pp[7]))) +
              (((pp[8] + pp[9]) + (pp[10] + pp[11])) + ((pp[12] + pp[13]) + (pp[14] + pp[15])));
      pb[0] = pack8(pp[0], pp[1], pp[2], pp[3], pp[4], pp[5], pp[6], pp[7]);
      pb[1] = pack8(pp[8], pp[9], pp[10], pp[11], pp[12], pp[13], pp[14], pp[15]);
    }
    {
      float pp[16];
      #pragma unroll
      for (int r = 0; r < 16; ++r) pp[r] = fexp2(st1[r]);
      lsum += (((pp[0] + pp[1]) + (pp[2] + pp[3])) + ((pp[4] + pp[5]) + (pp[6] + pp[7]))) +
              (((pp[8] + pp[9]) + (pp[10] + pp[11])) + ((pp[12] + pp[13]) + (pp[14] + pp[15])));
      pb[2] = pack8(pp[0], pp[1], pp[2], pp[3], pp[4], pp[5], pp[6], pp[7]);
      pb[3] = pack8(pp[8], pp[9], pp[10], pp[11], pp[12], pp[13], pp[14], pp[15]);
    }

    // ---- O^T += V^T P^T ----
    __builtin_amdgcn_s_setprio(1);
    #pragma unroll
    for (int cg = 0; cg < 4; ++cg) {
      const short* vp = &Vl[buf][(cg * 32 + l31) * 64];
      #pragma unroll
      for (int kc2 = 0; kc2 < 4; ++kc2) {
        s8b av = *(const s8b*)&vp[((kc2 * 2 + h) ^ x7) * 8];
        O[cg] = mfma32(av, pb[kc2], O[cg]);
      }
    }
    __builtin_amdgcn_s_setprio(0);
    __syncthreads();
  }

  // ---- l: combine the two half-lanes sharing a q-row ----
  lsum += __shfl_xor(lsum, 32);

  // ---- epilogue: O^T -> LDS transpose (reuse Kl) -> coalesced global ----
  short* eb = &Kl[0][0] + w * 4096;   // 32 rows x 128 ch bf16, groups swizzled by (n&7)
  #pragma unroll
  for (int cg = 0; cg < 4; ++cg)
    #pragma unroll
    for (int rp = 0; rp < 8; ++rp) {
      int r = rp * 2;
      int chlo = (r & 3) + 4 * h;          // within-8 offset (even)
      int chhi = cg * 4 + (r >> 2);        // 8-short group index
      *(unsigned*)&eb[l31 * 128 + ((chhi ^ x7)) * 8 + chlo] = cvtpk(O[cg][r], O[cg][r + 1]);
    }
  short* ob = Op + (size_t)kh * OPSTRIDE + ((size_t)(b * NSP + qt * 128)) * CCH;
  float* lp = Lp + kh * LPSTRIDE + b * NSP + qt * 128;
  if (lane < 32) lp[w * 32 + l31] = lsum;
  __syncthreads();
  for (int idx = t; idx < 128 * 16; idx += 256) {
    int row = idx >> 4, c8 = idx & 15;
    int w2 = row >> 5, nl = row & 31;
    *(s8b*)(ob + (size_t)row * CCH + c8 * 8) =
        *(const s8b*)(&Kl[0][0] + w2 * 4096 + nl * 128 + ((c8 ^ (nl & 7))) * 8);
  }
}

// ---------------- proj + bias + residual, merging the 4 kh partials ----------------
__global__ void proj_gemm(const short* __restrict__ Op, const float* __restrict__ Lp,
                          const float* __restrict__ Wp, const float* __restrict__ pbias,
                          const float* __restrict__ x, float* __restrict__ out) {
  int bx = blockIdx.x;            // 256 = b(4) nt(64)
  int nt = bx & 63, b = bx >> 6;
  __shared__ short Wl[128][136];
  int t = threadIdx.x;
  for (int idx = t; idx < 128 * 16; idx += 256) {
    int row = idx >> 4, c8 = idx & 15;
    const float* src = Wp + (size_t)row * CCH + c8 * 8;
    s8b wv;
    #pragma unroll
    for (int j = 0; j < 8; ++j) wv[j] = f2bf(src[j]);
    *(s8b*)&Wl[row][c8 * 8] = wv;
  }
  __syncthreads();
  int lane = t & 63, w = t >> 6, l15 = lane & 15, quad = lane >> 4;
  int row = nt * 64 + w * 16 + l15;             // this lane's ao row (m index)
  float lsum = 0.f;
  #pragma unroll
  for (int s = 0; s < KHN; ++s) lsum += Lp[(size_t)s * LPSTRIDE + b * NSP + row];
  float linv = 1.f / lsum;
  const short* ap = Op + ((size_t)(b * NSP + row)) * CCH + quad * 8;
  s8b bfr[4];
  #pragma unroll
  for (int kc = 0; kc < 4; ++kc) {
    float acc8[8];
    #pragma unroll
    for (int j = 0; j < 8; ++j) acc8[j] = 0.f;
    #pragma unroll
    for (int s = 0; s < KHN; ++s) {
      s8b tv = *(const s8b*)(ap + (size_t)s * OPSTRIDE + kc * 32);
      #pragma unroll
      for (int j = 0; j < 8; ++j) acc8[j] += bf2f(tv[j]);
    }
    #pragma unroll
    for (int j = 0; j < 8; ++j) bfr[kc][j] = f2bf(acc8[j] * linv);
  }
  #pragma unroll
  for (int cg = 0; cg < 8; ++cg) {
    f32x4 acc = {0.f, 0.f, 0.f, 0.f};
    #pragma unroll
    for (int kc = 0; kc < 4; ++kc) {
      s8b aw = *(const s8b*)&Wl[cg * 16 + l15][kc * 32 + quad * 8];
      acc = mfma16(aw, bfr[kc], acc);
    }
    #pragma unroll
    for (int r = 0; r < 4; ++r) {
      int co = cg * 16 + quad * 4 + r;
      int n = nt * 64 + w * 16 + l15;
      size_t off = ((size_t)(b * CCH + co)) * NSP + n;
      out[off] = x[off] + acc[r] + pbias[co];
    }
  }
}

extern "C" void kernel_launch(void* const* d_in, const int* in_sizes, int n_in,
                              void* d_out, int out_size, void* d_ws, size_t ws_size,
                              hipStream_t stream) {
  (void)in_sizes; (void)n_in; (void)out_size; (void)ws_size;
  const float* x    = (const float*)d_in[0];
  const float* gw   = (const float*)d_in[1];
  const float* gb   = (const float*)d_in[2];
  const float* Wqkv = (const float*)d_in[3];
  const float* bqkv = (const float*)d_in[4];
  const float* Wp   = (const float*)d_in[5];
  const float* bp   = (const float*)d_in[6];
  float* out = (float*)d_out;
  char* ws = (char*)d_ws;
  float* part = (float*)ws;                             // 512 floats
  short* xn    = (short*)(ws + 4096);
  short* q     = (short*)(ws + 4096 + 1ull * 4194304);
  short* k     = (short*)(ws + 4096 + 2ull * 4194304);
  short* vt    = (short*)(ws + 4096 + 3ull * 4194304);
  short* Opart = (short*)(ws + 4096 + 4ull * 4194304);  // 4 x 4MB bf16 partial O
  float* Lpart = (float*)(ws + 4096 + 8ull * 4194304);  // 4 x 64KB fp32 partial l

  gn_stats<<<256, 256, 0, stream>>>(x, part);
  gn_apply<<<256, 256, 0, stream>>>(x, gw, gb, part, xn);
  qkv_gemm<<<1280, 256, 0, stream>>>(xn, Wqkv, bqkv, q, k, vt);
  flash<<<512, 256, 0, stream>>>(q, k, vt, Opart, Lpart);
  proj_gemm<<<256, 256, 0, stream>>>(Opart, Lpart, Wp, bp, x, out);
}

// Round 4
// 133.995 us; speedup vs baseline: 2.0409x; 1.0031x over previous
//
#include <hip/hip_runtime.h>

#define BATCH 4
#define CCH 128
#define NSP 4096
#define NGRP 8
#define GROUP_ELEMS 65536   // 16 ch * 4096
// ATT_SCALE * log2(e): folded into q at qkv_gemm so softmax is exp2(s)
#define QSCALE 0.12751744f
#define EPS_GN 1e-5f
#define KHN 4               // key-split count (4 partials)
#define OPSTRIDE 2097152    // 4*4096*128 shorts per kh partial
#define LPSTRIDE 16384      // 4*4096 floats per kh partial

typedef short s8b __attribute__((ext_vector_type(8)));
typedef float f32x4 __attribute__((ext_vector_type(4)));
typedef float f32x16 __attribute__((ext_vector_type(16)));

static __device__ __forceinline__ short f2bf(float f) {
  union { float f; unsigned u; } v; v.f = f;
  unsigned r = (v.u + 0x7FFFu + ((v.u >> 16) & 1u)) >> 16;
  return (short)r;
}

static __device__ __forceinline__ float bf2f(short s) {
  unsigned u = ((unsigned)(unsigned short)s) << 16;
  float f; __builtin_memcpy(&f, &u, 4); return f;
}

static __device__ __forceinline__ float fexp2(float x) {
#if __has_builtin(__builtin_amdgcn_exp2f)
  return __builtin_amdgcn_exp2f(x);
#else
  return exp2f(x);
#endif
}

// single-instruction pack of two f32 -> adjacent bf16 (RNE): lo=a, hi=b
static __device__ __forceinline__ unsigned cvtpk(float a, float b) {
  unsigned r;
  asm("v_cvt_pk_bf16_f32 %0, %1, %2" : "=v"(r) : "v"(a), "v"(b));
  return r;
}

static __device__ __forceinline__ s8b pack8(float a0, float a1, float a2, float a3,
                                            float a4, float a5, float a6, float a7) {
  union { unsigned u[4]; s8b v; } x;
  x.u[0] = cvtpk(a0, a1); x.u[1] = cvtpk(a2, a3);
  x.u[2] = cvtpk(a4, a5); x.u[3] = cvtpk(a6, a7);
  return x.v;
}

static __device__ __forceinline__ f32x4 mfma16(s8b a, s8b b, f32x4 c) {
  return __builtin_amdgcn_mfma_f32_16x16x32_bf16(a, b, c, 0, 0, 0);
}
static __device__ __forceinline__ f32x16 mfma32(s8b a, s8b b, f32x16 c) {
  return __builtin_amdgcn_mfma_f32_32x32x16_bf16(a, b, c, 0, 0, 0);
}

// async 16B global->LDS DMA; dest = wave-uniform base + lane*16
static __device__ __forceinline__ void async16(const void* g, void* l) {
  __builtin_amdgcn_global_load_lds(
      (const __attribute__((address_space(1))) void*)g,
      (__attribute__((address_space(3))) void*)l, 16, 0, 0);
}

// ---------------- GroupNorm pass 1: per-(b,g,chunk) partial sum/sumsq ----------------
__global__ void gn_stats(const float* __restrict__ x, float* __restrict__ part) {
  int bx = blockIdx.x;            // 256 = bg(32) * chunk(8)
  int ch = bx & 7, bg = bx >> 3;
  const float* base = x + (size_t)bg * GROUP_ELEMS + (size_t)ch * 8192;
  int t = threadIdx.x;
  float s = 0.f, ss = 0.f;
  #pragma unroll
  for (int i = 0; i < 8; ++i) {
    float4 v = *(const float4*)(base + i * 1024 + t * 4);
    s  += v.x + v.y + v.z + v.w;
    ss += v.x * v.x + v.y * v.y + v.z * v.z + v.w * v.w;
  }
  #pragma unroll
  for (int off = 1; off < 64; off <<= 1) {
    s  += __shfl_xor(s, off);
    ss += __shfl_xor(ss, off);
  }
  __shared__ float red[8];
  int w = t >> 6;
  if ((t & 63) == 0) { red[w * 2] = s; red[w * 2 + 1] = ss; }
  __syncthreads();
  if (t == 0) {
    part[bx * 2]     = red[0] + red[2] + red[4] + red[6];
    part[bx * 2 + 1] = red[1] + red[3] + red[5] + red[7];
  }
}

// ---------------- GroupNorm pass 2: reduce partials, normalize, write xn (b,n,c) bf16 ----------------
__global__ void gn_apply(const float* __restrict__ x, const float* __restrict__ gw,
                         const float* __restrict__ gb, const float* __restrict__ part,
                         short* __restrict__ xn) {
  int bx = blockIdx.x;            // 256 = b(4) g(8) ns(8)
  int ns = bx & 7, g = (bx >> 3) & 7, b = bx >> 6;
  int bg = b * NGRP + g;
  float s = 0.f, ss = 0.f;
  #pragma unroll
  for (int j = 0; j < 8; ++j) {
    s  += part[(bg * 8 + j) * 2];
    ss += part[(bg * 8 + j) * 2 + 1];
  }
  float mean = s * (1.f / GROUP_ELEMS);
  float var  = ss * (1.f / GROUP_ELEMS) - mean * mean;
  float inv  = rsqrtf(var + EPS_GN);
  int t = threadIdx.x;
  int cl = t & 15, n4 = t >> 4;
  int c = g * 16 + cl;
  float ga = gw[c] * inv;
  float be = gb[c] - mean * ga;
  const float* xr = x + (size_t)(b * CCH + c) * NSP;
  short* xo = xn + (size_t)b * NSP * CCH + c;
  #pragma unroll
  for (int i = 0; i < 8; ++i) {
    int n = ns * 512 + i * 64 + n4 * 4;
    float4 v = *(const float4*)(xr + n);
    xo[(size_t)(n + 0) * CCH] = f2bf(v.x * ga + be);
    xo[(size_t)(n + 1) * CCH] = f2bf(v.y * ga + be);
    xo[(size_t)(n + 2) * CCH] = f2bf(v.z * ga + be);
    xo[(size_t)(n + 3) * CCH] = f2bf(v.w * ga + be);
  }
}

// ---------------- Fused QKV: bx<1024 -> q,k (D[n][o]); else -> v (D[o][n], permuted key order) ----------------
// v is written TRANSPOSED (b,c,n); within each 16-key chunk the key order is
// permuted so flash's PV can consume P DIRECTLY from the S^T MFMA C-registers:
// orig key kk (0..15) -> pos = 8*((kk>>2)&1) + (kk&3) + 4*(kk>>3)
__global__ void qkv_gemm(const short* __restrict__ xn, const float* __restrict__ Wqkv,
                         const float* __restrict__ bias, short* __restrict__ q,
                         short* __restrict__ k, short* __restrict__ vt) {
  __shared__ short Xl[128 * 136];
  __shared__ short Wl[64 * 136];
  int bx = blockIdx.x;
  int t = threadIdx.x;
  int lane = t & 63, w = t >> 6, l15 = lane & 15, quad = lane >> 4;
  if (bx < 1024) {
    // ---------- q,k part ----------
    int ot = bx & 3, nt = (bx >> 2) & 63, b = bx >> 8;
    for (int idx = t; idx < 64 * 16; idx += 256) {
      int row = idx >> 4, c8 = idx & 15;
      *(s8b*)&Xl[row * 136 + c8 * 8] =
          *(const s8b*)(xn + ((size_t)(b * NSP + nt * 64 + row)) * CCH + c8 * 8);
    }
    for (int idx = t; idx < 64 * 16; idx += 256) {
      int row = idx >> 4, c8 = idx & 15;
      const float* src = Wqkv + (size_t)(ot * 64 + row) * CCH + c8 * 8;
      s8b wv;
      #pragma unroll
      for (int j = 0; j < 8; ++j) wv[j] = f2bf(src[j]);
      *(s8b*)&Wl[row * 136 + c8 * 8] = wv;
    }
    __syncthreads();
    s8b a[4];
    #pragma unroll
    for (int kc = 0; kc < 4; ++kc)
      a[kc] = *(const s8b*)&Xl[(w * 16 + l15) * 136 + kc * 32 + quad * 8];
    #pragma unroll
    for (int o4 = 0; o4 < 4; ++o4) {
      f32x4 acc = {0.f, 0.f, 0.f, 0.f};
      #pragma unroll
      for (int kc = 0; kc < 4; ++kc) {
        s8b bw = *(const s8b*)&Wl[(o4 * 16 + l15) * 136 + kc * 32 + quad * 8];
        acc = mfma16(a[kc], bw, acc);
      }
      int obase = ot * 64 + o4 * 16;
      short* dst = (obase < 128) ? q : k;
      float mulf = (obase < 128) ? QSCALE : 1.0f;
      int oc = obase - ((obase < 128) ? 0 : 128) + l15;
      float bs = bias[obase + l15];
      #pragma unroll
      for (int r = 0; r < 4; ++r) {
        int n = nt * 64 + w * 16 + quad * 4 + r;
        dst[((size_t)(b * NSP + n)) * CCH + oc] = f2bf((acc[r] + bs) * mulf);
      }
    }
  } else {
    // ---------- v part ----------
    int vbx = bx - 1024;            // 256 = b(4) nt(32) ot(2)
    int ot = vbx & 1, nt = (vbx >> 1) & 31, b = vbx >> 6;
    for (int idx = t; idx < 128 * 16; idx += 256) {
      int row = idx >> 4, c8 = idx & 15;
      *(s8b*)&Xl[row * 136 + c8 * 8] =
          *(const s8b*)(xn + ((size_t)(b * NSP + nt * 128 + row)) * CCH + c8 * 8);
    }
    for (int idx = t; idx < 64 * 16; idx += 256) {
      int row = idx >> 4, c8 = idx & 15;
      const float* src = Wqkv + (size_t)(256 + ot * 64 + row) * CCH + c8 * 8;
      s8b wv;
      #pragma unroll
      for (int j = 0; j < 8; ++j) wv[j] = f2bf(src[j]);
      *(s8b*)&Wl[row * 136 + c8 * 8] = wv;
    }
    __syncthreads();
    s8b a[4];
    #pragma unroll
    for (int kc = 0; kc < 4; ++kc)
      a[kc] = *(const s8b*)&Wl[(w * 16 + l15) * 136 + kc * 32 + quad * 8];
    float bs[4];
    #pragma unroll
    for (int r = 0; r < 4; ++r) bs[r] = bias[256 + ot * 64 + w * 16 + quad * 4 + r];
    // permuted position within the 16-key chunk (see header comment)
    int ppos = 8 * ((l15 >> 2) & 1) + (l15 & 3) + 4 * (l15 >> 3);
    #pragma unroll
    for (int ntile = 0; ntile < 8; ++ntile) {
      f32x4 acc = {0.f, 0.f, 0.f, 0.f};
      #pragma unroll
      for (int kc = 0; kc < 4; ++kc) {
        s8b bx2 = *(const s8b*)&Xl[(ntile * 16 + l15) * 136 + kc * 32 + quad * 8];
        acc = mfma16(a[kc], bx2, acc);
      }
      int npos = nt * 128 + ntile * 16 + ppos;
      #pragma unroll
      for (int r = 0; r < 4; ++r) {
        int og = ot * 64 + w * 16 + quad * 4 + r;     // v channel
        vt[((size_t)(b * CCH + og)) * NSP + npos] = f2bf(acc[r] + bs[r]);
      }
    }
  }
}

// ---------------- Flash attention v12: counted-vmcnt pipeline (T4), no barrier drain ----------------
// Grid 512 = qt(32: 128-row tiles) x b(4) x kh(4 key quarters); 2 blocks/CU.
// Block 256 thr = 4 waves x 32 q-rows. Computes S^T = K Q^T (A=K, B=Q) so the
// C-layout (col=q-row, row=key) is directly a legal B-operand for
// O^T = V^T P^T after exp2+cvt_pk (V's in-chunk key permutation from
// qkv_gemm makes the C-reg key order match the B k-slot order). No P LDS.
// NEW vs v11: __syncthreads (which drains vmcnt to 0, killing the prefetch)
// replaced by raw s_barrier + COUNTED s_waitcnt vmcnt(8): two tiles stay in
// flight, the current tile's 8 loads are waited, the next tile's 8 ride
// through the whole compute phase. STAGE for tile i+2 is issued AFTER the
// read-fence barrier (it overwrites the buffer consumed this iteration).
// Sync-structure-edit risk class (m152): revert to drained variant on fail.
__global__ __launch_bounds__(256, 2) void flash(const short* __restrict__ q,
                                                const short* __restrict__ k,
                                                const short* __restrict__ vt,
                                                short* __restrict__ Op,
                                                float* __restrict__ Lp) {
  int bx = blockIdx.x;
  int kh = bx & 3, b = (bx >> 2) & 3, qt = bx >> 4;
  __shared__ short Kl[2][64 * 128];   // [key][ch], 8-short groups XOR-swizzled by (key&15)
  __shared__ short Vl[2][128 * 64];   // [ch][pos], 8-short groups XOR-swizzled by (ch&7)
  int t = threadIdx.x;
  int lane = t & 63, w = t >> 6;
  int l31 = lane & 31, h = lane >> 5;
  int x15 = l31 & 15, x7 = l31 & 7;
  const short* kbase = k + (size_t)b * NSP * CCH;
  const short* vbase = vt + (size_t)b * CCH * NSP;
  int kt0 = kh * 1024;

  int krow_in_chunk = lane >> 4, kgrp = lane & 15;
  int vrow_in_chunk = lane >> 3, vgrp = lane & 7;

  // Q B-fragments, resident: qrow = qt*128 + w*32 + l31, c = h*8 + 16*kc
  s8b aq[8];
  {
    const short* qp = q + ((size_t)(b * NSP + qt * 128 + w * 32 + l31)) * CCH + h * 8;
    #pragma unroll
    for (int kc = 0; kc < 8; ++kc) aq[kc] = *(const s8b*)(qp + kc * 16);
  }
  f32x16 O[4];
  #pragma unroll
  for (int cg = 0; cg < 4; ++cg)
    #pragma unroll
    for (int r = 0; r < 16; ++r) O[cg][r] = 0.f;
  float lsum = 0.f;

  // 8 async16 per wave per STAGE (4 si x {K,V})
  #define STAGE(buf_, key0_)                                                        \
    {                                                                               \
      const int key0v = (key0_);                                                    \
      _Pragma("unroll") for (int si = 0; si < 4; ++si) {                            \
        int c = w * 4 + si;                                                         \
        int rt = c * 4 + krow_in_chunk;                                             \
        async16(kbase + (size_t)(key0v + rt) * CCH + ((kgrp ^ (rt & 15)) * 8),      \
                &Kl[buf_][c * 512]);                                                \
        int rc = c * 8 + vrow_in_chunk;                                             \
        async16(vbase + (size_t)rc * NSP + key0v + ((vgrp ^ (rc & 7)) * 8),         \
                &Vl[buf_][c * 512]);                                                \
      }                                                                             \
    }

  // depth-2 prologue: tiles 0 and 1 in flight (16 outstanding loads/wave)
  STAGE(0, kt0)
  STAGE(1, kt0 + 64)

  for (int i = 0; i < 16; ++i) {
    int buf = i & 1;
    // current tile's 8 loads are the oldest; keep the next tile's 8 in flight.
    if (i < 15) {
      asm volatile("s_waitcnt vmcnt(8)\n\ts_barrier" ::: "memory");
    } else {
      asm volatile("s_waitcnt vmcnt(0)\n\ts_barrier" ::: "memory");
    }

    // ---- S^T = K Q^T over both 32-key tiles, two interleaved chains ----
    f32x16 st0, st1;
    #pragma unroll
    for (int r = 0; r < 16; ++r) { st0[r] = 0.f; st1[r] = 0.f; }
    const short* kp0 = &Kl[buf][(l31) * 128];
    const short* kp1 = &Kl[buf][(32 + l31) * 128];
    __builtin_amdgcn_s_setprio(1);
    #pragma unroll
    for (int kc = 0; kc < 8; ++kc) {
      int go = ((kc * 2 + h) ^ x15) * 8;
      s8b ak0 = *(const s8b*)&kp0[go];
      s8b ak1 = *(const s8b*)&kp1[go];
      st0 = mfma32(ak0, aq[kc], st0);
      st1 = mfma32(ak1, aq[kc], st1);
    }
    __builtin_amdgcn_s_setprio(0);

    // ---- p = exp2(s); l accumulate; pack C-regs straight into B-operands ----
    s8b pb[4];
    {
      float pp[16];
      #pragma unroll
      for (int r = 0; r < 16; ++r) pp[r] = fexp2(st0[r]);
      lsum += (((pp[0] + pp[1]) + (pp[2] + pp[3])) + ((pp[4] + pp[5]) + (pp[6] + pp[7]))) +
              (((pp[8] + pp[9]) + (pp[10] + pp[11])) + ((pp[12] + pp[13]) + (pp[14] + pp[15])));
      pb[0] = pack8(pp[0], pp[1], pp[2], pp[3], pp[4], pp[5], pp[6], pp[7]);
      pb[1] = pack8(pp[8], pp[9], pp[10], pp[11], pp[12], pp[13], pp[14], pp[15]);
    }
    {
      float pp[16];
      #pragma unroll
      for (int r = 0; r < 16; ++r) pp[r] = fexp2(st1[r]);
      lsum += (((pp[0] + pp[1]) + (pp[2] + pp[3])) + ((pp[4] + pp[5]) + (pp[6] + pp[7]))) +
              (((pp[8] + pp[9]) + (pp[10] + pp[11])) + ((pp[12] + pp[13]) + (pp[14] + pp[15])));
      pb[2] = pack8(pp[0], pp[1], pp[2], pp[3], pp[4], pp[5], pp[6], pp[7]);
      pb[3] = pack8(pp[8], pp[9], pp[10], pp[11], pp[12], pp[13], pp[14], pp[15]);
    }

    // ---- O^T += V^T P^T ----
    __builtin_amdgcn_s_setprio(1);
    #pragma unroll
    for (int cg = 0; cg < 4; ++cg) {
      const short* vp = &Vl[buf][(cg * 32 + l31) * 64];
      #pragma unroll
      for (int kc2 = 0; kc2 < 4; ++kc2) {
        s8b av = *(const s8b*)&vp[((kc2 * 2 + h) ^ x7) * 8];
        O[cg] = mfma32(av, pb[kc2], O[cg]);
      }
    }
    __builtin_amdgcn_s_setprio(0);

    // read-fence: all waves done reading buf before anyone overwrites it
    asm volatile("s_waitcnt lgkmcnt(0)\n\ts_barrier" ::: "memory");
    // stage tile i+2 into the buffer just consumed (rides through next iter)
    if (i < 14) STAGE(buf, kt0 + (i + 2) * 64)
  }

  // ---- l: combine the two half-lanes sharing a q-row ----
  lsum += __shfl_xor(lsum, 32);

  // ---- epilogue: O^T -> LDS transpose (reuse Kl) -> coalesced global ----
  // (safe: loop's final lgkmcnt(0)+s_barrier synced all waves' LDS reads)
  short* eb = &Kl[0][0] + w * 4096;   // 32 rows x 128 ch bf16, groups swizzled by (n&7)
  #pragma unroll
  for (int cg = 0; cg < 4; ++cg)
    #pragma unroll
    for (int rp = 0; rp < 8; ++rp) {
      int r = rp * 2;
      int chlo = (r & 3) + 4 * h;          // within-8 offset (even)
      int chhi = cg * 4 + (r >> 2);        // 8-short group index
      *(unsigned*)&eb[l31 * 128 + ((chhi ^ x7)) * 8 + chlo] = cvtpk(O[cg][r], O[cg][r + 1]);
    }
  short* ob = Op + (size_t)kh * OPSTRIDE + ((size_t)(b * NSP + qt * 128)) * CCH;
  float* lp = Lp + kh * LPSTRIDE + b * NSP + qt * 128;
  if (lane < 32) lp[w * 32 + l31] = lsum;
  __syncthreads();
  for (int idx = t; idx < 128 * 16; idx += 256) {
    int row = idx >> 4, c8 = idx & 15;
    int w2 = row >> 5, nl = row & 31;
    *(s8b*)(ob + (size_t)row * CCH + c8 * 8) =
        *(const s8b*)(&Kl[0][0] + w2 * 4096 + nl * 128 + ((c8 ^ (nl & 7))) * 8);
  }
}

// ---------------- proj + bias + residual, merging the 4 kh partials ----------------
__global__ void proj_gemm(const short* __restrict__ Op, const float* __restrict__ Lp,
                          const float* __restrict__ Wp, const float* __restrict__ pbias,
                          const float* __restrict__ x, float* __restrict__ out) {
  int bx = blockIdx.x;            // 256 = b(4) nt(64)
  int nt = bx & 63, b = bx >> 6;
  __shared__ short Wl[128][136];
  int t = threadIdx.x;
  for (int idx = t; idx < 128 * 16; idx += 256) {
    int row = idx >> 4, c8 = idx & 15;
    const float* src = Wp + (size_t)row * CCH + c8 * 8;
    s8b wv;
    #pragma unroll
    for (int j = 0; j < 8; ++j) wv[j] = f2bf(src[j]);
    *(s8b*)&Wl[row][c8 * 8] = wv;
  }
  __syncthreads();
  int lane = t & 63, w = t >> 6, l15 = lane & 15, quad = lane >> 4;
  int row = nt * 64 + w * 16 + l15;             // this lane's ao row (m index)
  float lsum = 0.f;
  #pragma unroll
  for (int s = 0; s < KHN; ++s) lsum += Lp[(size_t)s * LPSTRIDE + b * NSP + row];
  float linv = 1.f / lsum;
  const short* ap = Op + ((size_t)(b * NSP + row)) * CCH + quad * 8;
  s8b bfr[4];
  #pragma unroll
  for (int kc = 0; kc < 4; ++kc) {
    float acc8[8];
    #pragma unroll
    for (int j = 0; j < 8; ++j) acc8[j] = 0.f;
    #pragma unroll
    for (int s = 0; s < KHN; ++s) {
      s8b tv = *(const s8b*)(ap + (size_t)s * OPSTRIDE + kc * 32);
      #pragma unroll
      for (int j = 0; j < 8; ++j) acc8[j] += bf2f(tv[j]);
    }
    #pragma unroll
    for (int j = 0; j < 8; ++j) bfr[kc][j] = f2bf(acc8[j] * linv);
  }
  #pragma unroll
  for (int cg = 0; cg < 8; ++cg) {
    f32x4 acc = {0.f, 0.f, 0.f, 0.f};
    #pragma unroll
    for (int kc = 0; kc < 4; ++kc) {
      s8b aw = *(const s8b*)&Wl[cg * 16 + l15][kc * 32 + quad * 8];
      acc = mfma16(aw, bfr[kc], acc);
    }
    #pragma unroll
    for (int r = 0; r < 4; ++r) {
      int co = cg * 16 + quad * 4 + r;
      int n = nt * 64 + w * 16 + l15;
      size_t off = ((size_t)(b * CCH + co)) * NSP + n;
      out[off] = x[off] + acc[r] + pbias[co];
    }
  }
}

extern "C" void kernel_launch(void* const* d_in, const int* in_sizes, int n_in,
                              void* d_out, int out_size, void* d_ws, size_t ws_size,
                              hipStream_t stream) {
  (void)in_sizes; (void)n_in; (void)out_size; (void)ws_size;
  const float* x    = (const float*)d_in[0];
  const float* gw   = (const float*)d_in[1];
  const float* gb   = (const float*)d_in[2];
  const float* Wqkv = (const float*)d_in[3];
  const float* bqkv = (const float*)d_in[4];
  const float* Wp   = (const float*)d_in[5];
  const float* bp   = (const float*)d_in[6];
  float* out = (float*)d_out;
  char* ws = (char*)d_ws;
  float* part = (float*)ws;                             // 512 floats
  short* xn    = (short*)(ws + 4096);
  short* q     = (short*)(ws + 4096 + 1ull * 4194304);
  short* k     = (short*)(ws + 4096 + 2ull * 4194304);
  short* vt    = (short*)(ws + 4096 + 3ull * 4194304);
  short* Opart = (short*)(ws + 4096 + 4ull * 4194304);  // 4 x 4MB bf16 partial O
  float* Lpart = (float*)(ws + 4096 + 8ull * 4194304);  // 4 x 64KB fp32 partial l

  gn_stats<<<256, 256, 0, stream>>>(x, part);
  gn_apply<<<256, 256, 0, stream>>>(x, gw, gb, part, xn);
  qkv_gemm<<<1280, 256, 0, stream>>>(xn, Wqkv, bqkv, q, k, vt);
  flash<<<512, 256, 0, stream>>>(q, k, vt, Opart, Lpart);
  proj_gemm<<<256, 256, 0, stream>>>(Opart, Lpart, Wp, bp, x, out);
}